// Round 10
// baseline (253.467 us; speedup 1.0000x reference)
//
#include <hip/hip_runtime.h>
#include <hip/hip_bf16.h>

#define NIN   128
#define NOUT  64
#define RANK  10
#define NPAIR 5
#define WLEN  101
#define TLEN  50000
#define TILE  512
#define NTT   98
#define TPAD  (NTT * TILE)   // 50176
#define CBOFF 561
#define RROW  648            // f16 per RS row (stride 1296B: 324 dwords)
#define RROWD 324
#define NA    51             // fallback
#define XS    616            // fallback
#define KLDS  (NA * 20)      // fallback

typedef _Float16 h2 __attribute__((ext_vector_type(2)));
typedef _Float16 half8 __attribute__((ext_vector_type(8)));
typedef float f32x4 __attribute__((ext_vector_type(4)));

__device__ __forceinline__ unsigned pk_rne(float lo, float hi) {
    h2 v; v.x = (_Float16)lo; v.y = (_Float16)hi;
    return __builtin_bit_cast(unsigned, v);
}
__device__ __forceinline__ unsigned packh(float lo, float hi) { return pk_rne(lo, hi); }
__device__ __forceinline__ h2 as_h2(unsigned u) { return __builtin_bit_cast(h2, u); }

#if defined(__has_builtin)
#if __has_builtin(__builtin_amdgcn_fdot2)
#define FDOT2(a, b, c) __builtin_amdgcn_fdot2((a), (b), (c), false)
#endif
#endif
#ifndef FDOT2
__device__ __forceinline__ float fdot2_sw(h2 a, h2 b, float c) {
    return fmaf((float)a.x, (float)b.x, fmaf((float)a.y, (float)b.y, c));
}
#define FDOT2(a, b, c) fdot2_sw((a), (b), (c))
#endif

// ---------------------------------------------------------------------------
// Tap matrix for MFMA: Af[32][128] f16, row = 2*rank + comp, zero-padded.
__global__ void k_prep_taps(const float* __restrict__ K, _Float16* __restrict__ Af) {
    int idx = blockIdx.x * 256 + threadIdx.x;
    if (idx >= 32 * 128) return;
    int row = idx >> 7, j = idx & 127;
    int rank = row >> 1, comp = row & 1;
    float v = (rank < RANK && j < WLEN) ? K[(rank * 2 + comp) * WLEN + j] : 0.f;
    Af[idx] = (_Float16)v;
}

// Fallback-path taps.
__global__ void k_prep(const float* __restrict__ K, unsigned* __restrict__ Kd2) {
    int idx = blockIdx.x * 256 + threadIdx.x;
    if (idx >= KLDS) return;
    int a = idx / 20, r = idx % 20;
    int k = r >> 1, comp = r & 1;
    int j0 = 2 * a, j1 = 2 * a + 1;
    float v0 = K[(k * 2 + comp) * WLEN + j0];
    float v1 = (j1 < WLEN) ? K[(k * 2 + comp) * WLEN + j1] : 0.f;
    Kd2[idx] = packh(v0, v1);
}

// ---------------------------------------------------------------------------
// Pass 1 (MFMA). RS[s][i] = f16(x[C - i - s]), C = t0 + CBOFF.
// B-frag: lane reads half8 at f16 index 511 - 16*tau + 8q0 - c - s + 32ks
// within RS[s]; fully unrolled it-loop -> one vaddr + imm offsets.
template <bool TAIL, bool STORE>
__global__ __launch_bounds__(256, 4) void k_conv(
        const float* __restrict__ X, const _Float16* __restrict__ Af,
        unsigned* __restrict__ c4, float* __restrict__ sums,
        float* __restrict__ sumsq) {
    __shared__ __align__(16) _Float16 RS[8][RROW];
    __shared__ float red1[4][RANK], red2[4][RANK];
    const int n = blockIdx.y, tid = threadIdx.x;
    const int tile = TAIL ? (NTT - 1) : blockIdx.x;
    const int t0 = tile * TILE;
    const float* Xn = X + (size_t)n * TLEN;
    const int C = t0 + CBOFF;

    unsigned* RSd = (unsigned*)&RS[0][0];
    if (TAIL || tile == 0) {
#pragma unroll
        for (int s = 0; s < 8; ++s)
            for (int d = tid; d < RROWD; d += 256) {
                int i0 = C - 2 * d - 1 - s;
                float a = (i0 >= 0 && i0 < TLEN) ? Xn[i0] : 0.f;
                float b = (i0 + 1 >= 0 && i0 + 1 < TLEN) ? Xn[i0 + 1] : 0.f;
                RSd[s * RROWD + d] = pk_rne(b, a);
            }
    } else {
#pragma unroll
        for (int s = 0; s < 8; ++s)
            for (int d = tid; d < RROWD; d += 256) {
                int i0 = C - 2 * d - 1 - s;
                float a = Xn[i0], b = Xn[i0 + 1];
                RSd[s * RROWD + d] = pk_rne(b, a);
            }
    }
    __syncthreads();

    const int lane = tid & 63, wid = tid >> 6;
    const int c = lane & 15, q0 = lane >> 4;
    const int s = (7 - c) & 7;

    const half8* Ap = (const half8*)Af;
    half8 a0[4], a1[4];
#pragma unroll
    for (int ks = 0; ks < 4; ++ks) {
        a0[ks] = Ap[c * 16 + 4 * ks + q0];
        a1[ks] = Ap[(16 + c) * 16 + 4 * ks + q0];
    }

    const int Q = ((511 + 8 * q0 - c - s) >> 3) - 16 * wid - 14; // base8 at it=7,ks=0
    const char* vbase = (const char*)RS + s * 1296 + 16 * Q;

    const int tbase = t0 + 128 * wid + c;
    unsigned* st0 = c4 + (size_t)(n * NPAIR + q0) * TPAD + tbase;
    unsigned* st1 = c4 + (size_t)(n * NPAIR + 4) * TPAD + tbase;

    float sa0 = 0, sb0 = 0, sa1 = 0, sb1 = 0;
    float sa2 = 0, sb2 = 0, sa3 = 0, sb3 = 0;
    float m10v[8], m11v[8];

#pragma unroll
    for (int it = 0; it < 8; ++it) {
        f32x4 acc0 = {0.f, 0.f, 0.f, 0.f};
        f32x4 acc1 = {0.f, 0.f, 0.f, 0.f};
#pragma unroll
        for (int ks = 0; ks < 4; ++ks) {
            half8 b = *(const half8*)(vbase + 32 * (7 - it) + 64 * ks);
            acc0 = __builtin_amdgcn_mfma_f32_16x16x32_f16(a0[ks], b, acc0, 0, 0, 0);
            acc1 = __builtin_amdgcn_mfma_f32_16x16x32_f16(a1[ks], b, acc1, 0, 0, 0);
        }
        float rr00 = fmaf(acc0[0], acc0[0], acc0[1] * acc0[1]);
        float rr01 = fmaf(acc0[2], acc0[2], acc0[3] * acc0[3]);
        float rr10 = fmaf(acc1[0], acc1[0], acc1[1] * acc1[1]);
        float rr11 = fmaf(acc1[2], acc1[2], acc1[3] * acc1[3]);
        float m00 = sqrtf(rr00), m01 = sqrtf(rr01);
        float m10 = sqrtf(rr10), m11 = sqrtf(rr11);
        if (TAIL) {
            float g = (tbase + 16 * it < TLEN) ? 1.f : 0.f;
            sa0 = fmaf(g, m00, sa0); sb0 = fmaf(g, rr00, sb0);
            sa1 = fmaf(g, m01, sa1); sb1 = fmaf(g, rr01, sb1);
            sa2 = fmaf(g, m10, sa2); sb2 = fmaf(g, rr10, sb2);
            sa3 = fmaf(g, m11, sa3); sb3 = fmaf(g, rr11, sb3);
        } else {
            sa0 += m00; sb0 += rr00; sa1 += m01; sb1 += rr01;
            sa2 += m10; sb2 += rr10; sa3 += m11; sb3 += rr11;
        }
        m10v[it] = m10; m11v[it] = m11;
        if (STORE) st0[16 * it] = pk_rne(m00, m01);
    }
    if (STORE && q0 == 0) {
#pragma unroll
        for (int it = 0; it < 8; ++it)
            st1[16 * it] = pk_rne(m10v[it], m11v[it]);
    }
#pragma unroll
    for (int m = 1; m <= 8; m <<= 1) {
        sa0 += __shfl_xor(sa0, m); sb0 += __shfl_xor(sb0, m);
        sa1 += __shfl_xor(sa1, m); sb1 += __shfl_xor(sb1, m);
        sa2 += __shfl_xor(sa2, m); sb2 += __shfl_xor(sb2, m);
        sa3 += __shfl_xor(sa3, m); sb3 += __shfl_xor(sb3, m);
    }
    if (c == 0) {
        red1[wid][2 * q0] = sa0;     red2[wid][2 * q0] = sb0;
        red1[wid][2 * q0 + 1] = sa1; red2[wid][2 * q0 + 1] = sb1;
        if (q0 == 0) {
            red1[wid][8] = sa2; red2[wid][8] = sb2;
            red1[wid][9] = sa3; red2[wid][9] = sb3;
        }
    }
    __syncthreads();
    if (tid < RANK) {
        atomicAdd(&sums[n * RANK + tid],
                  red1[0][tid] + red1[1][tid] + red1[2][tid] + red1[3][tid]);
    } else if (tid >= 64 && tid < 64 + RANK) {
        int k = tid - 64;
        atomicAdd(&sumsq[n * RANK + k],
                  red2[0][k] + red2[1][k] + red2[2][k] + red2[3][k]);
    }
}

// ---------------------------------------------------------------------------
__global__ void k_fin(const float* __restrict__ sums,
                      const float* __restrict__ sumsq,
                      const float* __restrict__ B1,
                      const float* __restrict__ B2,
                      const float* __restrict__ bias,
                      float* __restrict__ Wm,
                      float* __restrict__ bias2) {
    __shared__ float mw[NIN * RANK];
    int tid = threadIdx.x;
    for (int idx = tid; idx < NIN * RANK; idx += 256) {
        float s = sums[idx], s2 = sumsq[idx];
        float mean = s / (float)TLEN;
        float var = fmaxf((s2 - s * mean) / (float)(TLEN - 1), 1e-12f);
        float w = B1[idx] / sqrtf(var);
        Wm[idx] = w;
        mw[idx] = mean * w;
    }
    __syncthreads();
    if (tid < NOUT) {
        float acc = bias[tid];
        for (int n = 0; n < NIN; ++n)
#pragma unroll
            for (int k = 0; k < RANK; ++k)
                acc -= mw[n * RANK + k] * B2[k * NOUT + tid];
        bias2[tid] = acc;
    }
}

// ---------------------------------------------------------------------------
// Pass 2 (BIG): c rows [n*5+p][t] dwords = (f16 c[2p][t], f16 c[2p+1][t]).
// grid (TPAD/512, 8): thread owns 2 t, n-chunk 16.
__global__ __launch_bounds__(256, 4) void k_comb(
        const unsigned* __restrict__ c4, const float* __restrict__ Wm,
        float* __restrict__ ypart) {
    __shared__ float wl[16 * RANK];
    const int tid = threadIdx.x, ch = blockIdx.y;
    const int n0 = ch * 16;
    if (tid < 16 * RANK) wl[tid] = Wm[n0 * RANK + tid];
    __syncthreads();
    const int t = 2 * (blockIdx.x * 256 + tid);
    const unsigned* pr = c4 + (size_t)(n0 * NPAIR) * TPAD + t;
    float2 y[RANK];
#pragma unroll
    for (int k = 0; k < RANK; ++k) y[k] = make_float2(0.f, 0.f);
#pragma unroll 2
    for (int nn = 0; nn < 16; ++nn) {
#pragma unroll
        for (int p = 0; p < NPAIR; ++p) {
            uint2 u = *(const uint2*)pr;
            pr += TPAD;
            h2 v0 = as_h2(u.x);
            h2 v1 = as_h2(u.y);
            float2 w = *(const float2*)&wl[nn * RANK + 2 * p];
            y[2 * p].x     = fmaf(w.x, (float)v0.x, y[2 * p].x);
            y[2 * p].y     = fmaf(w.x, (float)v1.x, y[2 * p].y);
            y[2 * p + 1].x = fmaf(w.y, (float)v0.y, y[2 * p + 1].x);
            y[2 * p + 1].y = fmaf(w.y, (float)v1.y, y[2 * p + 1].y);
        }
    }
#pragma unroll
    for (int k = 0; k < RANK; ++k)
        *(float2*)&ypart[(size_t)(ch * RANK + k) * TPAD + t] = y[k];
}

// ---------------------------------------------------------------------------
// Fallback conv core (fdot2) — used when ws can't hold c.
__device__ __forceinline__ void stage_Rp(const float* __restrict__ Xn,
                                         unsigned* Rs, int tstart) {
    for (int p = threadIdx.x; p < XS; p += 256) {
        int s = tstart - 55 + p;
        float x0 = (s >= 0 && s < TLEN) ? Xn[s] : 0.f;
        float x1 = (s + 1 >= 0 && s + 1 < TLEN) ? Xn[s + 1] : 0.f;
        Rs[p] = packh(x1, x0);
    }
}

__device__ __forceinline__ void conv_all(const unsigned* Rs, const unsigned* Kl,
                                         int tid,
                                         float (&re)[RANK][2],
                                         float (&im)[RANK][2]) {
#pragma unroll
    for (int k = 0; k < RANK; ++k) {
        re[k][0] = 0.f; re[k][1] = 0.f; im[k][0] = 0.f; im[k][1] = 0.f;
    }
    int pb = 2 * tid + 104;
#pragma unroll 1
    for (int ap = 0; ap < 25; ++ap) {
        int p = pb - 4 * ap;
        uint2 wA = *(const uint2*)&Rs[p];
        uint2 wB = *(const uint2*)&Rs[p - 2];
        h2 e0 = as_h2(wA.x), e1 = as_h2(wA.y);
        h2 o0 = as_h2(wB.x), o1 = as_h2(wB.y);
        const uint4* t0 = (const uint4*)&Kl[40 * ap];
        const uint4* t1 = (const uint4*)&Kl[40 * ap + 20];
#pragma unroll
        for (int kp = 0; kp < 5; ++kp) {
            const int k0 = 2 * kp, k1 = 2 * kp + 1;
            uint4 ta = t0[kp];
            h2 r0 = as_h2(ta.x), i0 = as_h2(ta.y);
            h2 r1 = as_h2(ta.z), i1 = as_h2(ta.w);
            re[k0][0] = FDOT2(e0, r0, re[k0][0]); im[k0][0] = FDOT2(e0, i0, im[k0][0]);
            re[k0][1] = FDOT2(e1, r0, re[k0][1]); im[k0][1] = FDOT2(e1, i0, im[k0][1]);
            re[k1][0] = FDOT2(e0, r1, re[k1][0]); im[k1][0] = FDOT2(e0, i1, im[k1][0]);
            re[k1][1] = FDOT2(e1, r1, re[k1][1]); im[k1][1] = FDOT2(e1, i1, im[k1][1]);
            uint4 tb = t1[kp];
            h2 s0 = as_h2(tb.x), j0 = as_h2(tb.y);
            h2 s1 = as_h2(tb.z), j1 = as_h2(tb.w);
            re[k0][0] = FDOT2(o0, s0, re[k0][0]); im[k0][0] = FDOT2(o0, j0, im[k0][0]);
            re[k0][1] = FDOT2(o1, s0, re[k0][1]); im[k0][1] = FDOT2(o1, j0, im[k0][1]);
            re[k1][0] = FDOT2(o0, s1, re[k1][0]); im[k1][0] = FDOT2(o0, j1, im[k1][0]);
            re[k1][1] = FDOT2(o1, s1, re[k1][1]); im[k1][1] = FDOT2(o1, j1, im[k1][1]);
        }
    }
    {
        int p = pb - 100;
        uint2 wA = *(const uint2*)&Rs[p];
        h2 e0 = as_h2(wA.x), e1 = as_h2(wA.y);
        const uint4* t0 = (const uint4*)&Kl[1000];
#pragma unroll
        for (int kp = 0; kp < 5; ++kp) {
            const int k0 = 2 * kp, k1 = 2 * kp + 1;
            uint4 ta = t0[kp];
            h2 r0 = as_h2(ta.x), i0 = as_h2(ta.y);
            h2 r1 = as_h2(ta.z), i1 = as_h2(ta.w);
            re[k0][0] = FDOT2(e0, r0, re[k0][0]); im[k0][0] = FDOT2(e0, i0, im[k0][0]);
            re[k0][1] = FDOT2(e1, r0, re[k0][1]); im[k0][1] = FDOT2(e1, i0, im[k0][1]);
            re[k1][0] = FDOT2(e0, r1, re[k1][0]); im[k1][0] = FDOT2(e0, i1, im[k1][0]);
            re[k1][1] = FDOT2(e1, r1, re[k1][1]); im[k1][1] = FDOT2(e1, i1, im[k1][1]);
        }
    }
}

__global__ __launch_bounds__(256, 4) void k_comb_re(const float* __restrict__ X,
                          const unsigned* __restrict__ Kd2,
                          const float* __restrict__ Wm,
                          float* __restrict__ ypart, int npc) {
    __shared__ __align__(16) unsigned Rs[XS];
    __shared__ __align__(16) unsigned Kl[KLDS];
    int chn = blockIdx.y, tile = blockIdx.x, tid = threadIdx.x;
    int tstart = tile * TILE;
    for (int idx = tid; idx < KLDS; idx += 256) Kl[idx] = Kd2[idx];
    float y[RANK][2];
#pragma unroll
    for (int k = 0; k < RANK; ++k) { y[k][0] = 0.f; y[k][1] = 0.f; }
    int n0 = chn * npc;
#pragma unroll 1
    for (int nn = 0; nn < npc; ++nn) {
        int n = n0 + nn;
        stage_Rp(X + (size_t)n * TLEN, Rs, tstart);
        __syncthreads();
        float re[RANK][2], im[RANK][2];
        conv_all(Rs, Kl, tid, re, im);
#pragma unroll
        for (int k = 0; k < RANK; ++k) {
            float w = Wm[n * RANK + k];
            float v0 = sqrtf(fmaf(re[k][0], re[k][0], im[k][0] * im[k][0]));
            float v1 = sqrtf(fmaf(re[k][1], re[k][1], im[k][1] * im[k][1]));
            y[k][0] = fmaf(v0, w, y[k][0]);
            y[k][1] = fmaf(v1, w, y[k][1]);
        }
        __syncthreads();
    }
    int tb = tstart + 2 * tid;
#pragma unroll
    for (int k = 0; k < RANK; ++k)
        *(float2*)&ypart[((size_t)(chn * RANK + k)) * TPAD + tb] =
            make_float2(y[k][0], y[k][1]);
}

// ---------------------------------------------------------------------------
// Final: out[m,t] = bias2[m] + sum_k B2[k,m] * sum_ch ypart[ch,k,t].
__global__ __launch_bounds__(256, 2) void k_out(const float* __restrict__ ypart,
                      const float* __restrict__ B2,
                      const float* __restrict__ bias2,
                      float* __restrict__ out, int nch) {
    __shared__ float b2l[RANK * NOUT];
    __shared__ float bl[NOUT];
    const int tid = threadIdx.x;
    for (int i = tid; i < RANK * NOUT; i += 256) b2l[i] = B2[i];
    if (tid < NOUT) bl[tid] = bias2[tid];
    __syncthreads();
    const int t = 2 * (blockIdx.x * 256 + tid);
    float2 y[RANK];
#pragma unroll
    for (int k = 0; k < RANK; ++k) y[k] = make_float2(0.f, 0.f);
    for (int ch = 0; ch < nch; ++ch)
#pragma unroll
        for (int k = 0; k < RANK; ++k) {
            float2 v = *(const float2*)&ypart[(size_t)(ch * RANK + k) * TPAD + t];
            y[k].x += v.x; y[k].y += v.y;
        }
    if (t < TLEN) {
#pragma unroll 1
        for (int m = 0; m < NOUT; ++m) {
            float ax = bl[m], ay = bl[m];
#pragma unroll
            for (int k = 0; k < RANK; ++k) {
                float w = b2l[k * NOUT + m];
                ax = fmaf(w, y[k].x, ax);
                ay = fmaf(w, y[k].y, ay);
            }
            *(float2*)&out[(size_t)m * TLEN + t] = make_float2(ax, ay);
        }
    }
}

// ---------------------------------------------------------------------------
extern "C" void kernel_launch(void* const* d_in, const int* in_sizes, int n_in,
                              void* d_out, int out_size, void* d_ws, size_t ws_size,
                              hipStream_t stream) {
    const float* X    = (const float*)d_in[0];
    const float* K    = (const float*)d_in[1];
    const float* B1   = (const float*)d_in[2];
    const float* B2   = (const float*)d_in[3];
    const float* bias = (const float*)d_in[4];
    float* out = (float*)d_out;

    char* p = (char*)d_ws;
    size_t off = 0;
    auto alloc = [&](size_t bytes) -> void* {
        void* r = p + off;
        off += (bytes + 255) & ~(size_t)255;
        return r;
    };
    float* sums  = (float*)alloc(NIN * RANK * sizeof(float));
    float* sumsq = (float*)alloc(NIN * RANK * sizeof(float));
    float* Wm    = (float*)alloc(NIN * RANK * sizeof(float));
    float* bias2 = (float*)alloc(NOUT * sizeof(float));
    unsigned* Kd2 = (unsigned*)alloc(KLDS * sizeof(unsigned));
    _Float16* Af  = (_Float16*)alloc(32 * 128 * sizeof(_Float16));

    size_t cbytes = (size_t)NIN * NPAIR * TPAD * sizeof(unsigned); // 128.45 MB
    auto ypb = [](int n) {
        return (((size_t)n * RANK * TPAD * sizeof(float)) + 255) & ~(size_t)255;
    };

    int mode, nch;
    if (ws_size >= off + ypb(8) + cbytes) { mode = 0; nch = 8; }
    else if (ws_size >= off + ypb(8))     { mode = 1; nch = 8; }
    else                                  { mode = 1; nch = 1; }

    float* ypart = (float*)alloc((size_t)nch * RANK * TPAD * sizeof(float));
    unsigned* c4 = (unsigned*)(p + off);  // BIG path only

    hipMemsetAsync(sums, 0, 2 * NIN * RANK * sizeof(float), stream);

    k_prep_taps<<<dim3(16), 256, 0, stream>>>(K, Af);
    if (mode == 1)
        k_prep<<<dim3((KLDS + 255) / 256), 256, 0, stream>>>(K, Kd2);

    if (mode == 0) {
        k_conv<false, true><<<dim3(NTT - 1, NIN), 256, 0, stream>>>(X, Af, c4, sums, sumsq);
        k_conv<true, true><<<dim3(1, NIN), 256, 0, stream>>>(X, Af, c4, sums, sumsq);
    } else {
        k_conv<false, false><<<dim3(NTT - 1, NIN), 256, 0, stream>>>(X, Af, c4, sums, sumsq);
        k_conv<true, false><<<dim3(1, NIN), 256, 0, stream>>>(X, Af, c4, sums, sumsq);
    }

    k_fin<<<1, 256, 0, stream>>>(sums, sumsq, B1, B2, bias, Wm, bias2);

    if (mode == 0) {
        k_comb<<<dim3(TPAD / 512, 8), 256, 0, stream>>>(c4, Wm, ypart);
        k_out<<<dim3(TPAD / 512), 256, 0, stream>>>(ypart, B2, bias2, out, 8);
    } else {
        k_comb_re<<<dim3(NTT, nch), 256, 0, stream>>>(X, Kd2, Wm, ypart, NIN / nch);
        k_out<<<dim3(TPAD / 512), 256, 0, stream>>>(ypart, B2, bias2, out, nch);
    }
}